// Round 3
// baseline (175.670 us; speedup 1.0000x reference)
//
#include <hip/hip_runtime.h>
#include <cstdint>

#define NSTARS 4096
#define NDIC   4096
#define NFEAT  16
#define NPIX   65536    // 256*256
#define BATCH  2048
#define BPB    128      // batch rows per k_opd block
#define NSEG   4        // d-segments in k_inter

using f32x4 = __attribute__((ext_vector_type(4))) float;

// ---------------------------------------------------------------------------
// Kernel A v2: fused lookup + partial inter sums.
// Grid: 512 row-quads x 4 d-segments = 2048 blocks (32 waves/CU occupancy).
// Each wave owns ONE batch row over a 1024-wide d-segment:
//   acc[16] per thread, 96-shfl reduction, no cross-wave combine.
// Output: partial[seg][row][16] in d_ws; k_opd sums the 4 segments.
// ---------------------------------------------------------------------------
__global__ __launch_bounds__(256) void k_inter(
    const float*  __restrict__ positions,   // [BATCH,2]
    const float2* __restrict__ obs,         // [NSTARS] as float2
    const float*  __restrict__ spatial,     // [NSTARS,NDIC]
    const float*  __restrict__ alpha,       // [NDIC,NFEAT]
    float*        __restrict__ partial)     // [NSEG][BATCH][NFEAT]
{
    __shared__ int s_idx[4];

    const int tid  = threadIdx.x;
    const int seg  = blockIdx.x & (NSEG - 1);
    const int q    = blockIdx.x >> 2;        // row quad [0, 512)
    const int wave = tid >> 6;
    const int lane = tid & 63;
    const int b0   = q * 4;

    if (tid < 4) s_idx[tid] = 0x7FFFFFFF;
    __syncthreads();

    // lookup: first flat-equal element row-major -> min star with x OR y match
    float px[4], py[4];
    #pragma unroll
    for (int b = 0; b < 4; ++b) {
        px[b] = positions[(b0 + b) * 2 + 0];
        py[b] = positions[(b0 + b) * 2 + 1];
    }
    for (int s = tid; s < NSTARS; s += 256) {
        float2 o = obs[s];
        #pragma unroll
        for (int b = 0; b < 4; ++b) {
            if (px[b] == o.x || py[b] == o.y) atomicMin(&s_idx[b], s);
        }
    }
    __syncthreads();

    int v = s_idx[wave];
    const int idx = (v == 0x7FFFFFFF) ? 0 : v;
    const int row = b0 + wave;

    const float*  srow   = spatial + (size_t)idx * NDIC + seg * 1024;
    const float4* alpha4 = (const float4*)alpha + (size_t)seg * 1024 * 4;

    float acc[NFEAT];
    #pragma unroll
    for (int f = 0; f < NFEAT; ++f) acc[f] = 0.0f;

    #pragma unroll
    for (int pass = 0; pass < 4; ++pass) {
        const int d = pass * 256 + lane * 4;      // [0, 1024) within segment
        const float4 vv = *(const float4*)(srow + d);
        #pragma unroll
        for (int k = 0; k < 4; ++k) {
            const float4 a0 = alpha4[(size_t)(d + k) * 4 + 0];
            const float4 a1 = alpha4[(size_t)(d + k) * 4 + 1];
            const float4 a2 = alpha4[(size_t)(d + k) * 4 + 2];
            const float4 a3 = alpha4[(size_t)(d + k) * 4 + 3];
            const float vb = (&vv.x)[k];
            acc[0]  += vb * a0.x;  acc[1]  += vb * a0.y;
            acc[2]  += vb * a0.z;  acc[3]  += vb * a0.w;
            acc[4]  += vb * a1.x;  acc[5]  += vb * a1.y;
            acc[6]  += vb * a1.z;  acc[7]  += vb * a1.w;
            acc[8]  += vb * a2.x;  acc[9]  += vb * a2.y;
            acc[10] += vb * a2.z;  acc[11] += vb * a2.w;
            acc[12] += vb * a3.x;  acc[13] += vb * a3.y;
            acc[14] += vb * a3.z;  acc[15] += vb * a3.w;
        }
    }

    // 64-lane butterfly: 6 levels x 16 feats = 96 shfl_xor
    #pragma unroll
    for (int off = 1; off < 64; off <<= 1)
        #pragma unroll
        for (int f = 0; f < NFEAT; ++f)
            acc[f] += __shfl_xor(acc[f], off);

    if (lane == 0) {
        float* p = partial + ((size_t)seg * BATCH + row) * NFEAT;
        *(float4*)(p + 0)  = make_float4(acc[0],  acc[1],  acc[2],  acc[3]);
        *(float4*)(p + 4)  = make_float4(acc[4],  acc[5],  acc[6],  acc[7]);
        *(float4*)(p + 8)  = make_float4(acc[8],  acc[9],  acc[10], acc[11]);
        *(float4*)(p + 12) = make_float4(acc[12], acc[13], acc[14], acc[15]);
    }
}

// ---------------------------------------------------------------------------
// Kernel B: out[b, pix] = sum_f (sum_seg partial[seg][b][f]) * S[f, pix]
// Identical structure to R2 (control) except w = sum of 4 segment partials.
// ---------------------------------------------------------------------------
__global__ __launch_bounds__(256) void k_opd(
    const f32x4* __restrict__ part4,    // [NSEG][BATCH][4] f32x4 rows
    const f32x4* __restrict__ S4,       // [NFEAT, NPIX/4]
    f32x4*       __restrict__ out4)     // [BATCH, NPIX/4]
{
    const int tid   = threadIdx.x;
    const int chunk = blockIdx.x & 63;       // pixel chunk (1024 px)
    const int bg    = blockIdx.x >> 6;       // batch group of BPB rows
    const int p4    = chunk * 256 + tid;     // float4 index in [0, 16384)

    f32x4 s[NFEAT];
    #pragma unroll
    for (int f = 0; f < NFEAT; ++f)
        s[f] = S4[(size_t)f * (NPIX / 4) + p4];

    f32x4* o = out4 + (size_t)bg * BPB * (NPIX / 4) + p4;

    #pragma unroll 2
    for (int b = 0; b < BPB; ++b) {
        const size_t bi = (size_t)bg * BPB + b;
        const f32x4 wa = part4[(0 * BATCH + bi) * 4 + 0] + part4[(1 * BATCH + bi) * 4 + 0]
                       + part4[(2 * BATCH + bi) * 4 + 0] + part4[(3 * BATCH + bi) * 4 + 0];
        const f32x4 wb = part4[(0 * BATCH + bi) * 4 + 1] + part4[(1 * BATCH + bi) * 4 + 1]
                       + part4[(2 * BATCH + bi) * 4 + 1] + part4[(3 * BATCH + bi) * 4 + 1];
        const f32x4 wc = part4[(0 * BATCH + bi) * 4 + 2] + part4[(1 * BATCH + bi) * 4 + 2]
                       + part4[(2 * BATCH + bi) * 4 + 2] + part4[(3 * BATCH + bi) * 4 + 2];
        const f32x4 wd = part4[(0 * BATCH + bi) * 4 + 3] + part4[(1 * BATCH + bi) * 4 + 3]
                       + part4[(2 * BATCH + bi) * 4 + 3] + part4[(3 * BATCH + bi) * 4 + 3];

        f32x4 acc = s[0] * wa.x;
        acc += s[1]  * wa.y;  acc += s[2]  * wa.z;  acc += s[3]  * wa.w;
        acc += s[4]  * wb.x;  acc += s[5]  * wb.y;  acc += s[6]  * wb.z;
        acc += s[7]  * wb.w;  acc += s[8]  * wc.x;  acc += s[9]  * wc.y;
        acc += s[10] * wc.z;  acc += s[11] * wc.w;  acc += s[12] * wd.x;
        acc += s[13] * wd.y;  acc += s[14] * wd.z;  acc += s[15] * wd.w;

        __builtin_nontemporal_store(acc, o + (size_t)b * (NPIX / 4));
    }
}

extern "C" void kernel_launch(void* const* d_in, const int* in_sizes, int n_in,
                              void* d_out, int out_size, void* d_ws, size_t ws_size,
                              hipStream_t stream) {
    const float*  positions = (const float*)d_in[0];   // [2048,2]
    const float2* obs       = (const float2*)d_in[1];  // [4096,2]
    const float*  spatial   = (const float*)d_in[2];   // [4096,4096]
    const float*  alpha     = (const float*)d_in[3];   // [4096,16]
    const f32x4*  S4        = (const f32x4*)d_in[4];   // [16,256,256]
    f32x4*        out       = (f32x4*)d_out;           // [2048,256,256]
    float*        partial   = (float*)d_ws;            // [4][2048][16] scratch

    k_inter<<<512 * NSEG, 256, 0, stream>>>(positions, obs, spatial, alpha, partial);
    k_opd<<<(NPIX / 1024) * (BATCH / BPB), 256, 0, stream>>>(
        (const f32x4*)partial, S4, out);
}

// Round 5
// 164.016 us; speedup vs baseline: 1.0711x; 1.0711x over previous
//
#include <hip/hip_runtime.h>
#include <cstdint>

#define NSTARS 4096
#define NDIC   4096
#define NFEAT  16
#define NPIX   65536    // 256*256
#define BATCH  2048
#define BPB    128      // batch rows per k_opd block

using f32x4 = __attribute__((ext_vector_type(4))) float;

// ---------------------------------------------------------------------------
// R5 = exact R2 (verified 146 us, passed post-timing) with ONE change:
// k_opd plain cached stores instead of nontemporal (fill kernel proves plain
// writes reach 6.58 TB/s at ~3 waves/CU; nt suspected to cap at ~4.7 TB/s).
// ---------------------------------------------------------------------------
__global__ __launch_bounds__(256) void k_inter(
    const float*  __restrict__ positions,   // [BATCH,2]
    const float2* __restrict__ obs,         // [NSTARS] as float2
    const float*  __restrict__ spatial,     // [NSTARS,NDIC]
    const float*  __restrict__ alpha,       // [NDIC,NFEAT]
    float*        __restrict__ inter)       // [BATCH,NFEAT] out
{
    __shared__ int   s_idx[4];
    __shared__ float s_red[4 * 64];

    const int tid = threadIdx.x;
    const int b0  = blockIdx.x * 4;

    if (tid < 4) s_idx[tid] = 0x7FFFFFFF;
    __syncthreads();

    float px[4], py[4];
    #pragma unroll
    for (int b = 0; b < 4; ++b) {
        px[b] = positions[(b0 + b) * 2 + 0];
        py[b] = positions[(b0 + b) * 2 + 1];
    }

    for (int s = tid; s < NSTARS; s += 256) {
        float2 o = obs[s];
        #pragma unroll
        for (int b = 0; b < 4; ++b) {
            if (px[b] == o.x || py[b] == o.y) atomicMin(&s_idx[b], s);
        }
    }
    __syncthreads();

    int idx[4];
    #pragma unroll
    for (int b = 0; b < 4; ++b) {
        int v = s_idx[b];
        idx[b] = (v == 0x7FFFFFFF) ? 0 : v;
    }

    float acc[4][NFEAT];
    #pragma unroll
    for (int b = 0; b < 4; ++b)
        #pragma unroll
        for (int f = 0; f < NFEAT; ++f) acc[b][f] = 0.0f;

    const float4* alpha4 = (const float4*)alpha;

    #pragma unroll
    for (int step = 0; step < 4; ++step) {
        const int d0 = tid * 4 + step * 1024;
        float4 v[4];
        #pragma unroll
        for (int b = 0; b < 4; ++b)
            v[b] = *(const float4*)(spatial + (size_t)idx[b] * NDIC + d0);

        #pragma unroll
        for (int k = 0; k < 4; ++k) {
            const float4 a0 = alpha4[(size_t)(d0 + k) * 4 + 0];
            const float4 a1 = alpha4[(size_t)(d0 + k) * 4 + 1];
            const float4 a2 = alpha4[(size_t)(d0 + k) * 4 + 2];
            const float4 a3 = alpha4[(size_t)(d0 + k) * 4 + 3];
            #pragma unroll
            for (int b = 0; b < 4; ++b) {
                const float vb = (&v[b].x)[k];
                acc[b][0]  += vb * a0.x;  acc[b][1]  += vb * a0.y;
                acc[b][2]  += vb * a0.z;  acc[b][3]  += vb * a0.w;
                acc[b][4]  += vb * a1.x;  acc[b][5]  += vb * a1.y;
                acc[b][6]  += vb * a1.z;  acc[b][7]  += vb * a1.w;
                acc[b][8]  += vb * a2.x;  acc[b][9]  += vb * a2.y;
                acc[b][10] += vb * a2.z;  acc[b][11] += vb * a2.w;
                acc[b][12] += vb * a3.x;  acc[b][13] += vb * a3.y;
                acc[b][14] += vb * a3.z;  acc[b][15] += vb * a3.w;
            }
        }
    }

    #pragma unroll
    for (int b = 0; b < 4; ++b)
        #pragma unroll
        for (int f = 0; f < NFEAT; ++f) {
            float x = acc[b][f];
            #pragma unroll
            for (int off = 32; off > 0; off >>= 1)
                x += __shfl_down(x, off);
            acc[b][f] = x;
        }

    const int lane = tid & 63;
    const int wave = tid >> 6;
    if (lane == 0) {
        #pragma unroll
        for (int b = 0; b < 4; ++b)
            #pragma unroll
            for (int f = 0; f < NFEAT; ++f)
                s_red[wave * 64 + b * NFEAT + f] = acc[b][f];
    }
    __syncthreads();

    if (tid < 64) {
        const int b = tid >> 4, f = tid & 15;
        float x = s_red[0 * 64 + tid] + s_red[1 * 64 + tid]
                + s_red[2 * 64 + tid] + s_red[3 * 64 + tid];
        inter[(size_t)(b0 + b) * NFEAT + f] = x;
    }
}

__global__ __launch_bounds__(256) void k_opd(
    const float4* __restrict__ inter4,  // [BATCH, 4] float4 rows
    const f32x4*  __restrict__ S4,      // [NFEAT, NPIX/4]
    f32x4*        __restrict__ out4)    // [BATCH, NPIX/4]
{
    const int tid   = threadIdx.x;
    const int chunk = blockIdx.x & 63;       // pixel chunk (1024 px)
    const int bg    = blockIdx.x >> 6;       // batch group of BPB rows
    const int p4    = chunk * 256 + tid;     // float4 index in [0, 16384)

    f32x4 s[NFEAT];
    #pragma unroll
    for (int f = 0; f < NFEAT; ++f)
        s[f] = S4[(size_t)f * (NPIX / 4) + p4];

    const float4* w4 = inter4 + (size_t)bg * BPB * 4;
    f32x4* o = out4 + (size_t)bg * BPB * (NPIX / 4) + p4;

    #pragma unroll 2
    for (int b = 0; b < BPB; ++b) {
        const float4 wa = w4[b * 4 + 0];
        const float4 wb = w4[b * 4 + 1];
        const float4 wc = w4[b * 4 + 2];
        const float4 wd = w4[b * 4 + 3];

        f32x4 acc = s[0] * wa.x;
        acc += s[1]  * wa.y;  acc += s[2]  * wa.z;  acc += s[3]  * wa.w;
        acc += s[4]  * wb.x;  acc += s[5]  * wb.y;  acc += s[6]  * wb.z;
        acc += s[7]  * wb.w;  acc += s[8]  * wc.x;  acc += s[9]  * wc.y;
        acc += s[10] * wc.z;  acc += s[11] * wc.w;  acc += s[12] * wd.x;
        acc += s[13] * wd.y;  acc += s[14] * wd.z;  acc += s[15] * wd.w;

        o[(size_t)b * (NPIX / 4)] = acc;   // plain cached store (was nt)
    }
}

extern "C" void kernel_launch(void* const* d_in, const int* in_sizes, int n_in,
                              void* d_out, int out_size, void* d_ws, size_t ws_size,
                              hipStream_t stream) {
    const float*  positions = (const float*)d_in[0];   // [2048,2]
    const float2* obs       = (const float2*)d_in[1];  // [4096,2]
    const float*  spatial   = (const float*)d_in[2];   // [4096,4096]
    const float*  alpha     = (const float*)d_in[3];   // [4096,16]
    const f32x4*  S4        = (const f32x4*)d_in[4];   // [16,256,256]
    f32x4*        out       = (f32x4*)d_out;           // [2048,256,256]
    float*        inter     = (float*)d_ws;            // [2048,16] scratch

    k_inter<<<BATCH / 4, 256, 0, stream>>>(positions, obs, spatial, alpha, inter);
    k_opd<<<(NPIX / 1024) * (BATCH / BPB), 256, 0, stream>>>(
        (const float4*)inter, S4, out);
}